// Round 22
// baseline (105.507 us; speedup 1.0000x reference)
//
#include <hip/hip_runtime.h>
#include <hip/hip_bf16.h>

constexpr int NN  = 4096;       // n_node + 1 == batch
constexpr int DE  = 32;         // d_emb
constexpr int TD  = 2048;       // T*D

typedef __attribute__((ext_vector_type(8))) short short8;
typedef __attribute__((ext_vector_type(4))) float f32x4;

#define MFMA16(a, b, c) __builtin_amdgcn_mfma_f32_16x16x32_bf16(a, b, c, 0, 0, 0)

__device__ inline ushort f2b(float x) {
    __hip_bfloat16 h = __float2bfloat16(x);
    union { __hip_bfloat16 h; ushort u; } c; c.h = h;
    return c.u;
}

__device__ inline float b2f(ushort u) {
    union { unsigned u; float f; } c; c.u = ((unsigned)u) << 16;
    return c.f;
}

__device__ inline short8 pack8(float4 a, float4 b) {
    short8 v;
    v[0] = (short)f2b(a.x); v[1] = (short)f2b(a.y); v[2] = (short)f2b(a.z); v[3] = (short)f2b(a.w);
    v[4] = (short)f2b(b.x); v[5] = (short)f2b(b.y); v[6] = (short)f2b(b.z); v[7] = (short)f2b(b.w);
    return v;
}

__device__ inline short8 pack8v(f32x4 a, f32x4 b) {
    short8 v;
    v[0] = (short)f2b(a[0]); v[1] = (short)f2b(a[1]); v[2] = (short)f2b(a[2]); v[3] = (short)f2b(a[3]);
    v[4] = (short)f2b(b[0]); v[5] = (short)f2b(b[1]); v[6] = (short)f2b(b[2]); v[7] = (short)f2b(b[3]);
    return v;
}

__device__ __forceinline__ short8 as_s8(f32x4 v) {
    union { f32x4 f; short8 s; } u; u.f = v; return u.s;
}

template<int OFF>
__device__ __forceinline__ f32x4 gl16(unsigned long long addr) {
    f32x4 d;
    asm volatile("global_load_dwordx4 %0, %1, off offset:%c2"
                 : "=v"(d) : "v"(addr), "n"(OFF) : "memory");
    return d;
}

template<int OFF>
__device__ __forceinline__ float gl4(unsigned long long addr) {
    float d;
    asm volatile("global_load_dword %0, %1, off offset:%c2"
                 : "=v"(d) : "v"(addr), "n"(OFF) : "memory");
    return d;
}

#define WAITV(N) asm volatile("s_waitcnt vmcnt(" #N ")" ::: "memory"); \
                 __builtin_amdgcn_sched_barrier(0)

// ================= k_prep: s | embbf | WeTT | W cvt x3  (224 blocks) =================
__global__ __launch_bounds__(256) void k_prep(const float* __restrict__ emb,
                                              const float* __restrict__ We,
                                              const float* __restrict__ Wk,
                                              const float* __restrict__ Wv,
                                              const float* __restrict__ Wo,
                                              float* __restrict__ s_g,
                                              ushort* __restrict__ embbf,
                                              ushort* __restrict__ WeTT,
                                              ushort* __restrict__ Wkbf,
                                              ushort* __restrict__ Wvbf,
                                              ushort* __restrict__ Wobf) {
    int id = blockIdx.x, tid = threadIdx.x;
    if (id < 16) {                                   // ---- s[n]
        int n = id * 256 + tid;
        const float4* e4 = (const float4*)(emb + (size_t)n * DE);
        float s = 0.f;
#pragma unroll
        for (int i = 0; i < DE / 4; ++i) { float4 v = e4[i]; s += v.x + v.y + v.z + v.w; }
        s_g[n] = s;
    } else if (id < 144) {                           // ---- embbf (vectorized)
        int g4 = (id - 16) * 256 + tid;              // 0..32767
        float4 v = *(const float4*)&emb[(size_t)g4 * 4];
        ushort4 o; o.x = f2b(v.x); o.y = f2b(v.y); o.z = f2b(v.z); o.w = f2b(v.w);
        *(ushort4*)&embbf[(size_t)g4 * 4] = o;
    } else if (id < 176) {                           // ---- WeTT: contiguous read, scattered write
        int e = id - 144;                            // 0..31
#pragma unroll
        for (int u = 0; u < 4; ++u) {
            int idx0 = tid * 16 + u * 4;
            float4 v = *(const float4*)&We[(size_t)e * 4096 + idx0];
            float vv[4] = {v.x, v.y, v.z, v.w};
#pragma unroll
            for (int i = 0; i < 4; ++i) {
                int idx = idx0 + i;
                int o = idx & 63, d = idx >> 6;
                WeTT[(size_t)(o * 64 + d) * 32 + e] = f2b(vv[i]);
            }
        }
    } else {                                         // ---- Wk/Wv/Wo bf16 [176,224)
        int id5 = id - 176;
        int which = id5 >> 4, gid = (id5 & 15) * 256 + tid;   // 0..4095
        const float* src = which == 0 ? Wk : (which == 1 ? Wv : Wo);
        ushort* dst = which == 0 ? Wkbf : (which == 1 ? Wvbf : Wobf);
        dst[gid] = f2b(src[gid]);
    }
}

// ===== k_pr: proj(q) [0,512) | rank [512,1024) | wnodem [1024,2048) | bnode [2048,2064) =====
__global__ __launch_bounds__(256) void k_pr(const float* __restrict__ X,
                                            const float* __restrict__ W,
                                            const float* __restrict__ bias,
                                            ushort* __restrict__ Y,
                                            const float* __restrict__ s_g,
                                            int* __restrict__ perm,
                                            const ushort* __restrict__ embbf,
                                            const ushort* __restrict__ WeTT,
                                            ushort* __restrict__ WnT,
                                            const float* __restrict__ be,
                                            float* __restrict__ bn) {
    __shared__ float ss[NN];
    int id = blockIdx.x, tid = threadIdx.x;
    if (id < 512) {
        int lane = tid & 63, wid = tid >> 6;
        int r0 = id * 256 + wid * 64;
        int l15 = lane & 15, kb = lane >> 4;
        f32x4 acc[4][4] = {};
#pragma unroll
        for (int kk = 0; kk < 2; ++kk) {
            short8 af[4], bf[4];
#pragma unroll
            for (int f = 0; f < 4; ++f) {
                const float* ap = X + (size_t)(r0 + f * 16 + l15) * 64 + kk * 32 + kb * 8;
                af[f] = pack8(*(const float4*)ap, *(const float4*)(ap + 4));
                const float* bp = W + (size_t)(f * 16 + l15) * 64 + kk * 32 + kb * 8;
                bf[f] = pack8(*(const float4*)bp, *(const float4*)(bp + 4));
            }
#pragma unroll
            for (int i = 0; i < 4; ++i)
#pragma unroll
                for (int j = 0; j < 4; ++j)
                    acc[i][j] = MFMA16(af[i], bf[j], acc[i][j]);
        }
        float bcol[4];
#pragma unroll
        for (int j = 0; j < 4; ++j) bcol[j] = bias[j * 16 + l15];
#pragma unroll
        for (int i = 0; i < 4; ++i)
#pragma unroll
            for (int j = 0; j < 4; ++j)
#pragma unroll
                for (int r = 0; r < 4; ++r)
                    Y[(size_t)(r0 + i * 16 + kb * 4 + r) * 64 + j * 16 + l15] =
                        f2b(acc[i][j][r] + bcol[j]);
    } else if (id < 1024) {
        for (int i = tid; i < NN; i += 256) ss[i] = s_g[i];
        __syncthreads();
        int g = tid >> 5, l = tid & 31;
        int n = (id - 512) * 8 + g;
        float sn = ss[n];
        int cnt = 0;
        for (int j2 = 0; j2 < 128; ++j2) {
            int m = j2 * 32 + l;
            float sm = ss[m];
            cnt += (sm < sn) || (sm == sn && m < n);
        }
        for (int off = 16; off; off >>= 1) cnt += __shfl_down(cnt, off, 32);
        if (l == 0) perm[cnt] = n;
    } else if (id < 2048) {                          // ---- wnodem (indep of chain)
        int w2 = id - 1024;
        int lane = tid & 63, wid = tid >> 6;
        int n0  = (w2 & 31) * 128 + (wid >> 1) * 64;
        int od0 = (w2 >> 5) * 128 + (wid & 1) * 64;
        int l15 = lane & 15, kb = lane >> 4;
        short8 af[4], bf[4];
#pragma unroll
        for (int f = 0; f < 4; ++f) {
            af[f] = *(const short8*)(embbf + (size_t)(n0 + f * 16 + l15) * 32 + kb * 8);
            bf[f] = *(const short8*)(WeTT + (size_t)(od0 + f * 16 + l15) * 32 + kb * 8);
        }
        f32x4 acc[4][4] = {};
#pragma unroll
        for (int i = 0; i < 4; ++i)
#pragma unroll
            for (int j = 0; j < 4; ++j)
                acc[i][j] = MFMA16(af[i], bf[j], acc[i][j]);
#pragma unroll
        for (int i = 0; i < 4; ++i)
#pragma unroll
            for (int j = 0; j < 4; ++j)
#pragma unroll
                for (int r = 0; r < 4; ++r)
                    WnT[(size_t)(n0 + i * 16 + kb * 4 + r) * 4096 + od0 + j * 16 + l15] =
                        f2b(acc[i][j][r]);
    } else {                                         // ---- bnode = embbf @ be^T (MFMA, K=32)
        int blk = id - 2048;
        int lane = tid & 63, wid = tid >> 6;
        int n0 = blk * 256 + wid * 64;
        int l15 = lane & 15, kb = lane >> 4;
        short8 af[4], bf[4];
#pragma unroll
        for (int f = 0; f < 4; ++f)
            af[f] = *(const short8*)(embbf + (size_t)(n0 + f * 16 + l15) * 32 + kb * 8);
#pragma unroll
        for (int j = 0; j < 4; ++j) {
            short8 v;
#pragma unroll
            for (int i = 0; i < 8; ++i)
                v[i] = (short)f2b(be[(kb * 8 + i) * 64 + j * 16 + l15]);
            bf[j] = v;
        }
        f32x4 acc[4][4] = {};
#pragma unroll
        for (int i = 0; i < 4; ++i)
#pragma unroll
            for (int j = 0; j < 4; ++j)
                acc[i][j] = MFMA16(af[i], bf[j], acc[i][j]);
#pragma unroll
        for (int i = 0; i < 4; ++i)
#pragma unroll
            for (int j = 0; j < 4; ++j)
#pragma unroll
                for (int r = 0; r < 4; ++r)
                    bn[(size_t)(n0 + i * 16 + kb * 4 + r) * 64 + j * 16 + l15] = acc[i][j][r];
    }
}

// ---------------- chunk sums (CHUNK=32): Cj[c][j][k] = sum b^k q[perm[i]][j] ------
__global__ __launch_bounds__(256) void k_csum(const ushort* __restrict__ qp,
                                              const float* __restrict__ s_g,
                                              const int* __restrict__ perm,
                                              float* __restrict__ Cj,
                                              float* __restrict__ Cb) {
    __shared__ int ns[32];
    __shared__ float bs[32];
    int bx = blockIdx.x, by = blockIdx.y, tid = threadIdx.x;
    if (tid < 32) {
        int n = perm[bx * 32 + tid];
        ns[tid] = n;
        bs[tid] = __expf(-s_g[n]);
    }
    __syncthreads();
    int j = by * 256 + tid;
    float run[8] = {};
    for (int ii = 0; ii < 32; ++ii) {
        float qv = b2f(qp[(size_t)ns[ii] * 2048 + j]);
        float b = bs[ii], t = qv;
#pragma unroll
        for (int k2 = 0; k2 < 8; ++k2) { run[k2] += t; t *= b; }
    }
    float* cp = Cj + ((size_t)bx * 2048 + j) * 8;
    *(float4*)cp       = make_float4(run[0], run[1], run[2], run[3]);
    *(float4*)(cp + 4) = make_float4(run[4], run[5], run[6], run[7]);
    if (by == 0 && tid < 32) {
        float b = bs[tid], bk = 1.f;
#pragma unroll
        for (int k2 = 0; k2 < 8; ++k2) {
            float v = bk;
            for (int off = 16; off; off >>= 1) v += __shfl_down(v, off, 32);
            if (tid == 0) Cb[bx * 8 + k2] = v;
            bk *= b;
        }
    }
}

// ---------------- prefix over 128 chunks (blocks 0..63) + Cb prefix (block 64) ----------
__global__ __launch_bounds__(256) void k_pre(const float* __restrict__ Cj,
                                             float* __restrict__ PRE,
                                             const float* __restrict__ Cb,
                                             float* __restrict__ CbPre) {
    __shared__ float sCb[1024];
    int tid = threadIdx.x;
    if (blockIdx.x < 64) {
        int gid = blockIdx.x * 256 + tid;          // 16384
        float run = 0.f;
#pragma unroll 8
        for (int c = 0; c < 128; ++c) {
            PRE[(size_t)c * 16384 + gid] = run;
            run += Cj[(size_t)c * 16384 + gid];
        }
        PRE[(size_t)128 * 16384 + gid] = run;
    } else {
        sCb[tid] = Cb[tid];
        sCb[tid + 256] = Cb[tid + 256];
        sCb[tid + 512] = Cb[tid + 512];
        sCb[tid + 768] = Cb[tid + 768];
        __syncthreads();
        if (tid < 8) {
            float run = 0.f;
            for (int c = 0; c < 128; ++c) {
                CbPre[c * 8 + tid] = run;
                run += sCb[c * 8 + tid];
            }
            CbPre[1024 + tid] = run;
        }
    }
}

// ====== k_combw: comb only (1024 blocks) ======
__global__ __launch_bounds__(256) void k_combw(const ushort* __restrict__ qp,
                                               const float* __restrict__ s_g,
                                               const int* __restrict__ perm,
                                               const float* __restrict__ PRE,
                                               const float* __restrict__ CbPre,
                                               ushort* __restrict__ qdifb) {
    __shared__ int ns[32];
    __shared__ float sa[32], sb[32];
    int id = blockIdx.x, tid = threadIdx.x;
    int bx = id & 127, by = id >> 7;
    if (tid < 32) {
        int n = perm[bx * 32 + tid];
        ns[tid] = n;
        float s = s_g[n];
        sa[tid] = __expf(s);
        sb[tid] = __expf(-s);
    }
    __syncthreads();
    int j = by * 256 + tid;
    float T[8], pre[8];
    {
        const float* pp = PRE + (size_t)bx * 16384 + (size_t)j * 8;
        float4 u0 = *(const float4*)pp, u1 = *(const float4*)(pp + 4);
        pre[0] = u0.x; pre[1] = u0.y; pre[2] = u0.z; pre[3] = u0.w;
        pre[4] = u1.x; pre[5] = u1.y; pre[6] = u1.z; pre[7] = u1.w;
        const float* tp = PRE + (size_t)128 * 16384 + (size_t)j * 8;
        float4 t0 = *(const float4*)tp, t1 = *(const float4*)(tp + 4);
        T[0] = t0.x; T[1] = t0.y; T[2] = t0.z; T[3] = t0.w;
        T[4] = t1.x; T[5] = t1.y; T[6] = t1.z; T[7] = t1.w;
    }
    float TB[8], preb[8];
    {
        float4 v0 = *(const float4*)&CbPre[bx * 8], v1 = *(const float4*)&CbPre[bx * 8 + 4];
        preb[0] = v0.x; preb[1] = v0.y; preb[2] = v0.z; preb[3] = v0.w;
        preb[4] = v1.x; preb[5] = v1.y; preb[6] = v1.z; preb[7] = v1.w;
        float4 t0 = *(const float4*)&CbPre[1024], t1 = *(const float4*)&CbPre[1028];
        TB[0] = t0.x; TB[1] = t0.y; TB[2] = t0.z; TB[3] = t0.w;
        TB[4] = t1.x; TB[5] = t1.y; TB[6] = t1.z; TB[7] = t1.w;
    }
#pragma unroll 2
    for (int ii = 0; ii < 32; ++ii) {
        int n = ns[ii];
        float a = sa[ii], b = sb[ii];
        float g0 = 0.36787944117144233f;       // e^{-1}
        float g1 = g0 * a;
        float g2 = g1 * a * 0.5f;
        float g3 = g2 * a * (1.f / 3.f);
        float g4 = g3 * a * 0.25f;
        float g5 = g4 * a * 0.2f;
        float g6 = g5 * a * (1.f / 6.f);
        float g7 = g6 * a * (1.f / 7.f);
        float Z = a * preb[1]
                + g0 * (TB[0] - preb[0]) + g1 * (TB[1] - preb[1])
                + g2 * (TB[2] - preb[2]) + g3 * (TB[3] - preb[3])
                + g4 * (TB[4] - preb[4]) + g5 * (TB[5] - preb[5])
                + g6 * (TB[6] - preb[6]) + g7 * (TB[7] - preb[7]);
        float izv = 1.f / Z;
        float qv = b2f(qp[(size_t)n * 2048 + j]);
        float ss2 = g0 * (T[0] - pre[0]) + g1 * (T[1] - pre[1])
                  + g2 * (T[2] - pre[2]) + g3 * (T[3] - pre[3])
                  + g4 * (T[4] - pre[4]) + g5 * (T[5] - pre[5])
                  + g6 * (T[6] - pre[6]) + g7 * (T[7] - pre[7]);
        float outv = (a * pre[1] + ss2) * izv + qv;
        qdifb[(size_t)n * 2048 + j] = f2b(outv);
        float bk = 1.f;
#pragma unroll
        for (int k2 = 0; k2 < 8; ++k2) { pre[k2] += bk * qv; preb[k2] += bk; bk *= b; }
    }
}

// ---- fused (r16/r18 version): 4 waves/batch (w0:K, w1:V, w2:Q(0,1), w3:Q(2,3)) ----
__global__ __launch_bounds__(256, 2) void k_fused(const float* __restrict__ kin,
                                                  const float* __restrict__ vin,
                                                  const ushort* __restrict__ qdifb,
                                                  const ushort* __restrict__ WnT,
                                                  const float* __restrict__ bn,
                                                  const ushort* __restrict__ Wkbf,
                                                  const float* __restrict__ bk,
                                                  const ushort* __restrict__ Wvbf,
                                                  const float* __restrict__ bv,
                                                  const ushort* __restrict__ Wobf,
                                                  const float* __restrict__ bo,
                                                  float* __restrict__ out) {
    __shared__ ushort Kb[2176];       // [h][s][d1]  h stride 272
    __shared__ ushort Qb[2176];
    __shared__ ushort Vb[2560];       // [h][d1][s]  h stride 320, d1 stride 40
    __shared__ ushort Pb[4][1280];    // per-wave [t][s] t stride 40
    __shared__ ushort attb[2304];     // [t][d64] stride 72
    int tid = threadIdx.x, lane = tid & 63, w = tid >> 6;
    int b = blockIdx.x;
    int l15 = lane & 15, g = lane >> 4;
    int hh_w = l15 >> 3, d1_w = l15 & 7;
    const float SCALE = 0.35355339059327373f;   // 1/sqrt(8)
    short8 zfrag = {};

    f32x4 wx0, wx1, wx2, wx3, wx4, wx5, wx6, wx7;
    f32x4 x0, x1, x2, x3, x4, x5, x6, x7;
    float bxc0, bxc1, bxc2, bxc3;
    f32x4 q0v, q1v, q2v, q3v;
    f32x4 wn0, wn1, wn2, wn3;
    float bnc0, bnc1;
    f32x4 wo0, wo1; float boc;

    if (w < 2) {
        const float*  xin = w ? vin : kin;
        const ushort* Wx  = w ? Wvbf : Wkbf;
        const float*  bx_ = w ? bv : bk;
        unsigned long long bxA = (unsigned long long)(bx_ + l15);
        unsigned long long wxA = (unsigned long long)((const char*)Wx + l15 * 128 + g * 16 + 3072);
        unsigned long long xaA = (unsigned long long)(xin + (size_t)b * TD + (8 + l15) * 64 + g * 8);
        bxc0 = gl4<0>(bxA); bxc1 = gl4<64>(bxA); bxc2 = gl4<128>(bxA); bxc3 = gl4<192>(bxA);
        wx0 = gl16<-3072>(wxA); wx1 = gl16<-3008>(wxA);
        wx2 = gl16<-1024>(wxA); wx3 = gl16< -960>(wxA);
        wx4 = gl16< 1024>(wxA); wx5 = gl16< 1088>(wxA);
        wx6 = gl16< 3072>(wxA); wx7 = gl16< 3136>(wxA);
        x0 = gl16<-2048>(xaA); x1 = gl16<-2032>(xaA);
        x2 = gl16<-1920>(xaA); x3 = gl16<-1904>(xaA);
        x4 = gl16< 2048>(xaA); x5 = gl16< 2064>(xaA);
        x6 = gl16< 2176>(xaA); x7 = gl16< 2192>(xaA);
    } else {
        int wq = w - 2;
        unsigned long long qaA = (unsigned long long)(qdifb + (size_t)b * TD + (8 + l15) * 64 + g * 8);
        unsigned long long wnA = (unsigned long long)((const char*)(WnT + (size_t)b * 4096)
                                                      + ((size_t)(wq * 32 + l15)) * 128 + g * 16);
        unsigned long long bnA = (unsigned long long)(bn + (size_t)b * 64 + wq * 32 + l15);
        q0v = gl16<-1024>(qaA); q1v = gl16<-960>(qaA);
        q2v = gl16< 1024>(qaA); q3v = gl16<1088>(qaA);
        wn0 = gl16<0>(wnA); wn1 = gl16<64>(wnA);
        wn2 = gl16<2048>(wnA); wn3 = gl16<2112>(wnA);
        bnc0 = gl4<0>(bnA); bnc1 = gl4<64>(bnA);
    }
    {   // epilogue loads last -> stay in flight through attention
        unsigned long long woA = (unsigned long long)((const char*)Wobf
                                                      + ((size_t)(w * 16 + l15)) * 128 + g * 16);
        unsigned long long boA = (unsigned long long)(bo + w * 16 + l15);
        wo0 = gl16<0>(woA); wo1 = gl16<64>(woA);
        boc = gl4<0>(boA);
    }

    if (w < 2) {
        WAITV(3);
        short8 xaf[2][2], wxf[4][2];
        xaf[0][0] = pack8v(x0, x1); xaf[1][0] = pack8v(x2, x3);
        xaf[0][1] = pack8v(x4, x5); xaf[1][1] = pack8v(x6, x7);
        wxf[0][0] = as_s8(wx0); wxf[0][1] = as_s8(wx1);
        wxf[1][0] = as_s8(wx2); wxf[1][1] = as_s8(wx3);
        wxf[2][0] = as_s8(wx4); wxf[2][1] = as_s8(wx5);
        wxf[3][0] = as_s8(wx6); wxf[3][1] = as_s8(wx7);
        float bxc[4] = {bxc0, bxc1, bxc2, bxc3};
#pragma unroll
        for (int j = 0; j < 4; ++j) {
            f32x4 ax[2] = {};
#pragma unroll
            for (int kk = 0; kk < 2; ++kk)
#pragma unroll
                for (int ti = 0; ti < 2; ++ti)
                    ax[ti] = MFMA16(xaf[kk][ti], wxf[j][kk], ax[ti]);
            if (w == 0) {
#pragma unroll
                for (int ti = 0; ti < 2; ++ti)
#pragma unroll
                    for (int r = 0; r < 4; ++r) {
                        int s = ti * 16 + g * 4 + r;
                        Kb[(j * 2 + hh_w) * 272 + s * 8 + d1_w] = f2b(ax[ti][r] + bxc[j]);
                    }
            } else {
#pragma unroll
                for (int ti = 0; ti < 2; ++ti)
#pragma unroll
                    for (int r = 0; r < 4; r += 2) {
                        int s = ti * 16 + g * 4 + r;
                        ushort2 p; p.x = f2b(ax[ti][r] + bxc[j]); p.y = f2b(ax[ti][r + 1] + bxc[j]);
                        *(ushort2*)&Vb[(j * 2 + hh_w) * 320 + d1_w * 40 + s] = p;
                    }
            }
        }
    } else {
        int wq = w - 2;
        WAITV(3);
        short8 qaf[2][2], wnf[2][2];
        qaf[0][0] = as_s8(q0v); qaf[1][0] = as_s8(q1v);
        qaf[0][1] = as_s8(q2v); qaf[1][1] = as_s8(q3v);
        wnf[0][0] = as_s8(wn0); wnf[0][1] = as_s8(wn1);
        wnf[1][0] = as_s8(wn2); wnf[1][1] = as_s8(wn3);
        float bnc[2] = {bnc0, bnc1};
#pragma unroll
        for (int jj = 0; jj < 2; ++jj) {
            int j = 2 * wq + jj;
            f32x4 aq[2] = {};
#pragma unroll
            for (int kk = 0; kk < 2; ++kk)
#pragma unroll
                for (int ti = 0; ti < 2; ++ti)
                    aq[ti] = MFMA16(qaf[kk][ti], wnf[jj][kk], aq[ti]);
#pragma unroll
            for (int ti = 0; ti < 2; ++ti)
#pragma unroll
                for (int r = 0; r < 4; ++r) {
                    int s = ti * 16 + g * 4 + r;
                    Qb[(j * 2 + hh_w) * 272 + s * 8 + d1_w] = f2b(aq[ti][r] + bnc[jj]);
                }
        }
    }
    __syncthreads();

    // ======== attention: 2 heads per wave (h = 2w, 2w+1) ========
#pragma unroll
    for (int hh = 0; hh < 2; ++hh) {
        int h = 2 * w + hh;
        short8 kf[2], qf[2];
#pragma unroll
        for (int si = 0; si < 2; ++si)
            kf[si] = (lane < 16) ? *(const short8*)&Kb[h * 272 + (si * 16 + l15) * 8] : zfrag;
#pragma unroll
        for (int ti = 0; ti < 2; ++ti)
            qf[ti] = (lane < 16) ? *(const short8*)&Qb[h * 272 + (ti * 16 + l15) * 8] : zfrag;
        f32x4 sc[2][2];
#pragma unroll
        for (int si = 0; si < 2; ++si)
#pragma unroll
            for (int ti = 0; ti < 2; ++ti)
                sc[si][ti] = MFMA16(kf[si], qf[ti], f32x4{});
#pragma unroll
        for (int ti = 0; ti < 2; ++ti) {
            float e0[4], e1[4], sm = 0.f;
#pragma unroll
            for (int r = 0; r < 4; ++r) {
                e0[r] = __expf(sc[0][ti][r] * SCALE);
                e1[r] = __expf(sc[1][ti][r] * SCALE);
                sm += e0[r] + e1[r];
            }
            sm += __shfl_xor(sm, 16);
            sm += __shfl_xor(sm, 32);
            float inv = 1.f / sm;
            int t = ti * 16 + l15;
            unsigned p00 = (unsigned)f2b(e0[0] * inv) | ((unsigned)f2b(e0[1] * inv) << 16);
            unsigned p01 = (unsigned)f2b(e0[2] * inv) | ((unsigned)f2b(e0[3] * inv) << 16);
            unsigned p10 = (unsigned)f2b(e1[0] * inv) | ((unsigned)f2b(e1[1] * inv) << 16);
            unsigned p11 = (unsigned)f2b(e1[2] * inv) | ((unsigned)f2b(e1[3] * inv) << 16);
            *(unsigned*)&Pb[w][t * 40 + g * 4]          = p00;
            *(unsigned*)&Pb[w][t * 40 + g * 4 + 2]      = p01;
            *(unsigned*)&Pb[w][t * 40 + 16 + g * 4]     = p10;
            *(unsigned*)&Pb[w][t * 40 + 16 + g * 4 + 2] = p11;
        }
        short8 vf = *(const short8*)&Vb[h * 320 + (l15 & 7) * 40 + g * 8];
#pragma unroll
        for (int ti = 0; ti < 2; ++ti) {
            short8 af = *(const short8*)&Pb[w][(ti * 16 + l15) * 40 + g * 8];
            f32x4 pv = MFMA16(af, vf, f32x4{});
            if (l15 < 8) {
#pragma unroll
                for (int r = 0; r < 4; ++r)
                    attb[(ti * 16 + g * 4 + r) * 72 + h * 8 + l15] = f2b(pv[r]);
            }
        }
    }
    __syncthreads();

    // ======== epilogue: this wave's column tile j = w ========
    WAITV(0);
    {
        short8 wof[2];
        wof[0] = as_s8(wo0); wof[1] = as_s8(wo1);
        short8 aof[2][2];
#pragma unroll
        for (int kk = 0; kk < 2; ++kk)
#pragma unroll
            for (int ti = 0; ti < 2; ++ti)
                aof[kk][ti] = *(const short8*)&attb[(ti * 16 + l15) * 72 + kk * 32 + g * 8];
        f32x4 co[2] = {};
#pragma unroll
        for (int kk = 0; kk < 2; ++kk)
#pragma unroll
            for (int ti = 0; ti < 2; ++ti)
                co[ti] = MFMA16(aof[kk][ti], wof[kk], co[ti]);
#pragma unroll
        for (int ti = 0; ti < 2; ++ti)
#pragma unroll
            for (int r = 0; r < 4; ++r)
                out[(size_t)b * TD + (ti * 16 + g * 4 + r) * 64 + w * 16 + l15] =
                    co[ti][r] + boc;
    }
}

extern "C" void kernel_launch(void* const* d_in, const int* in_sizes, int n_in,
                              void* d_out, int out_size, void* d_ws, size_t ws_size,
                              hipStream_t stream) {
    const float* q   = (const float*)d_in[0];
    const float* k   = (const float*)d_in[1];
    const float* v   = (const float*)d_in[2];
    const float* emb = (const float*)d_in[3];
    const float* We  = (const float*)d_in[4];
    const float* be  = (const float*)d_in[5];
    const float* Wq  = (const float*)d_in[6];
    const float* bq  = (const float*)d_in[7];
    const float* Wk  = (const float*)d_in[8];
    const float* bk  = (const float*)d_in[9];
    const float* Wv  = (const float*)d_in[10];
    const float* bv  = (const float*)d_in[11];
    const float* Wo  = (const float*)d_in[12];
    const float* bo  = (const float*)d_in[13];

    float* ws = (float*)d_ws;
    ushort* qp    = (ushort*)ws;                          // 16 MB (bf16)
    ushort* WnT   = (ushort*)(ws + 4194304);              // 32 MB
    ushort* qdifb = (ushort*)(ws + 12582912);             // 16 MB
    float*  Cj    = ws + 16777216;                        // 8 MB (128 chunks)
    float*  bn    = ws + 18874368;                        // 1 MB
    float*  s_g   = ws + 19136512;                        // 16 KB
    int*    perm  = (int*)(ws + 19140608);                // 16 KB
    float*  Cb    = ws + 19144704;                        // 4 KB
    ushort* embbf = (ushort*)(ws + 19145728);             // 256 KB
    ushort* WeTT  = (ushort*)(ws + 19211264);             // 256 KB
    ushort* Wkbf  = (ushort*)(ws + 19276800);             // 8 KB
    ushort* Wvbf  = (ushort*)(ws + 19278848);             // 8 KB
    ushort* Wobf  = (ushort*)(ws + 19280896);             // 8 KB
    float*  PRE   = ws + 19282944;                        // 8.45 MB (129 x 16384)
    float*  CbPre = ws + 21396480;                        // 4.1 KB (end ~85.6 MB)
    float*  outp  = (float*)d_out;

    k_prep <<<224, 256, 0, stream>>>(emb, We, Wk, Wv, Wo,
                                     s_g, embbf, WeTT, Wkbf, Wvbf, Wobf);
    k_pr   <<<2064, 256, 0, stream>>>(q, Wq, bq, qp, s_g, perm,
                                      embbf, WeTT, WnT, be, bn);
    k_csum <<<dim3(128, 8), 256, 0, stream>>>(qp, s_g, perm, Cj, Cb);
    k_pre  <<<65, 256, 0, stream>>>(Cj, PRE, Cb, CbPre);
    k_combw<<<1024, 256, 0, stream>>>(qp, s_g, perm, PRE, CbPre, qdifb);
    k_fused<<<4096, 256, 0, stream>>>(k, v, qdifb, WnT, bn,
                                      Wkbf, bk, Wvbf, bv, Wobf, bo, outp);
}

// Round 23
// 103.617 us; speedup vs baseline: 1.0182x; 1.0182x over previous
//
#include <hip/hip_runtime.h>
#include <hip/hip_bf16.h>

constexpr int NN  = 4096;       // n_node + 1 == batch
constexpr int DE  = 32;         // d_emb
constexpr int TD  = 2048;       // T*D

typedef __attribute__((ext_vector_type(8))) short short8;
typedef __attribute__((ext_vector_type(4))) float f32x4;

#define MFMA16(a, b, c) __builtin_amdgcn_mfma_f32_16x16x32_bf16(a, b, c, 0, 0, 0)

__device__ inline ushort f2b(float x) {
    __hip_bfloat16 h = __float2bfloat16(x);
    union { __hip_bfloat16 h; ushort u; } c; c.h = h;
    return c.u;
}

__device__ inline float b2f(ushort u) {
    union { unsigned u; float f; } c; c.u = ((unsigned)u) << 16;
    return c.f;
}

__device__ inline short8 pack8(float4 a, float4 b) {
    short8 v;
    v[0] = (short)f2b(a.x); v[1] = (short)f2b(a.y); v[2] = (short)f2b(a.z); v[3] = (short)f2b(a.w);
    v[4] = (short)f2b(b.x); v[5] = (short)f2b(b.y); v[6] = (short)f2b(b.z); v[7] = (short)f2b(b.w);
    return v;
}

__device__ inline short8 pack8v(f32x4 a, f32x4 b) {
    short8 v;
    v[0] = (short)f2b(a[0]); v[1] = (short)f2b(a[1]); v[2] = (short)f2b(a[2]); v[3] = (short)f2b(a[3]);
    v[4] = (short)f2b(b[0]); v[5] = (short)f2b(b[1]); v[6] = (short)f2b(b[2]); v[7] = (short)f2b(b[3]);
    return v;
}

__device__ __forceinline__ short8 as_s8(f32x4 v) {
    union { f32x4 f; short8 s; } u; u.f = v; return u.s;
}

template<int OFF>
__device__ __forceinline__ f32x4 gl16(unsigned long long addr) {
    f32x4 d;
    asm volatile("global_load_dwordx4 %0, %1, off offset:%c2"
                 : "=v"(d) : "v"(addr), "n"(OFF) : "memory");
    return d;
}

template<int OFF>
__device__ __forceinline__ float gl4(unsigned long long addr) {
    float d;
    asm volatile("global_load_dword %0, %1, off offset:%c2"
                 : "=v"(d) : "v"(addr), "n"(OFF) : "memory");
    return d;
}

#define WAITV(N) asm volatile("s_waitcnt vmcnt(" #N ")" ::: "memory"); \
                 __builtin_amdgcn_sched_barrier(0)

// ================= k_prep: s | embbf | WeTT | W cvt x3  (224 blocks) =================
__global__ __launch_bounds__(256) void k_prep(const float* __restrict__ emb,
                                              const float* __restrict__ We,
                                              const float* __restrict__ Wk,
                                              const float* __restrict__ Wv,
                                              const float* __restrict__ Wo,
                                              float* __restrict__ s_g,
                                              ushort* __restrict__ embbf,
                                              ushort* __restrict__ WeTT,
                                              ushort* __restrict__ Wkbf,
                                              ushort* __restrict__ Wvbf,
                                              ushort* __restrict__ Wobf) {
    int id = blockIdx.x, tid = threadIdx.x;
    if (id < 16) {                                   // ---- s[n]
        int n = id * 256 + tid;
        const float4* e4 = (const float4*)(emb + (size_t)n * DE);
        float s = 0.f;
#pragma unroll
        for (int i = 0; i < DE / 4; ++i) { float4 v = e4[i]; s += v.x + v.y + v.z + v.w; }
        s_g[n] = s;
    } else if (id < 144) {                           // ---- embbf (vectorized)
        int g4 = (id - 16) * 256 + tid;              // 0..32767
        float4 v = *(const float4*)&emb[(size_t)g4 * 4];
        ushort4 o; o.x = f2b(v.x); o.y = f2b(v.y); o.z = f2b(v.z); o.w = f2b(v.w);
        *(ushort4*)&embbf[(size_t)g4 * 4] = o;
    } else if (id < 176) {                           // ---- WeTT: contiguous read, scattered write
        int e = id - 144;                            // 0..31
#pragma unroll
        for (int u = 0; u < 4; ++u) {
            int idx0 = tid * 16 + u * 4;
            float4 v = *(const float4*)&We[(size_t)e * 4096 + idx0];
            float vv[4] = {v.x, v.y, v.z, v.w};
#pragma unroll
            for (int i = 0; i < 4; ++i) {
                int idx = idx0 + i;
                int o = idx & 63, d = idx >> 6;
                WeTT[(size_t)(o * 64 + d) * 32 + e] = f2b(vv[i]);
            }
        }
    } else {                                         // ---- Wk/Wv/Wo bf16 [176,224)
        int id5 = id - 176;
        int which = id5 >> 4, gid = (id5 & 15) * 256 + tid;   // 0..4095
        const float* src = which == 0 ? Wk : (which == 1 ? Wv : Wo);
        ushort* dst = which == 0 ? Wkbf : (which == 1 ? Wvbf : Wobf);
        dst[gid] = f2b(src[gid]);
    }
}

// ================= k_pr: projm(q)->bf16 [0,512) | rank [512,1024) =================
__global__ __launch_bounds__(256) void k_pr(const float* __restrict__ X,
                                            const float* __restrict__ W,
                                            const float* __restrict__ bias,
                                            ushort* __restrict__ Y,
                                            const float* __restrict__ s_g,
                                            int* __restrict__ perm) {
    __shared__ float ss[NN];
    int id = blockIdx.x, tid = threadIdx.x;
    if (id < 512) {
        int lane = tid & 63, wid = tid >> 6;
        int r0 = id * 256 + wid * 64;
        int l15 = lane & 15, kb = lane >> 4;
        f32x4 acc[4][4] = {};
#pragma unroll
        for (int kk = 0; kk < 2; ++kk) {
            short8 af[4], bf[4];
#pragma unroll
            for (int f = 0; f < 4; ++f) {
                const float* ap = X + (size_t)(r0 + f * 16 + l15) * 64 + kk * 32 + kb * 8;
                af[f] = pack8(*(const float4*)ap, *(const float4*)(ap + 4));
                const float* bp = W + (size_t)(f * 16 + l15) * 64 + kk * 32 + kb * 8;
                bf[f] = pack8(*(const float4*)bp, *(const float4*)(bp + 4));
            }
#pragma unroll
            for (int i = 0; i < 4; ++i)
#pragma unroll
                for (int j = 0; j < 4; ++j)
                    acc[i][j] = MFMA16(af[i], bf[j], acc[i][j]);
        }
        float bcol[4];
#pragma unroll
        for (int j = 0; j < 4; ++j) bcol[j] = bias[j * 16 + l15];
#pragma unroll
        for (int i = 0; i < 4; ++i)
#pragma unroll
            for (int j = 0; j < 4; ++j)
#pragma unroll
                for (int r = 0; r < 4; ++r)
                    Y[(size_t)(r0 + i * 16 + kb * 4 + r) * 64 + j * 16 + l15] =
                        f2b(acc[i][j][r] + bcol[j]);
    } else {
        for (int i = tid; i < NN; i += 256) ss[i] = s_g[i];
        __syncthreads();
        int g = tid >> 5, l = tid & 31;
        int n = (id - 512) * 8 + g;
        float sn = ss[n];
        int cnt = 0;
        for (int j2 = 0; j2 < 128; ++j2) {
            int m = j2 * 32 + l;
            float sm = ss[m];
            cnt += (sm < sn) || (sm == sn && m < n);
        }
        for (int off = 16; off; off >>= 1) cnt += __shfl_down(cnt, off, 32);
        if (l == 0) perm[cnt] = n;
    }
}

// ---------------- chunk sums (CHUNK=32): Cj[c][j][k] = sum b^k q[perm[i]][j] ------
__global__ __launch_bounds__(256) void k_csum(const ushort* __restrict__ qp,
                                              const float* __restrict__ s_g,
                                              const int* __restrict__ perm,
                                              float* __restrict__ Cj,
                                              float* __restrict__ Cb) {
    __shared__ int ns[32];
    __shared__ float bs[32];
    int bx = blockIdx.x, by = blockIdx.y, tid = threadIdx.x;
    if (tid < 32) {
        int n = perm[bx * 32 + tid];
        ns[tid] = n;
        bs[tid] = __expf(-s_g[n]);
    }
    __syncthreads();
    int j = by * 256 + tid;
    float run[8] = {};
    for (int ii = 0; ii < 32; ++ii) {
        float qv = b2f(qp[(size_t)ns[ii] * 2048 + j]);
        float b = bs[ii], t = qv;
#pragma unroll
        for (int k2 = 0; k2 < 8; ++k2) { run[k2] += t; t *= b; }
    }
    float* cp = Cj + ((size_t)bx * 2048 + j) * 8;
    *(float4*)cp       = make_float4(run[0], run[1], run[2], run[3]);
    *(float4*)(cp + 4) = make_float4(run[4], run[5], run[6], run[7]);
    if (by == 0 && tid < 32) {
        float b = bs[tid], bk = 1.f;
#pragma unroll
        for (int k2 = 0; k2 < 8; ++k2) {
            float v = bk;
            for (int off = 16; off; off >>= 1) v += __shfl_down(v, off, 32);
            if (tid == 0) Cb[bx * 8 + k2] = v;
            bk *= b;
        }
    }
}

// ---------------- prefix over 128 chunks (blocks 0..63) + Cb prefix (block 64) ----------
__global__ __launch_bounds__(256) void k_pre(const float* __restrict__ Cj,
                                             float* __restrict__ PRE,
                                             const float* __restrict__ Cb,
                                             float* __restrict__ CbPre) {
    __shared__ float sCb[1024];
    int tid = threadIdx.x;
    if (blockIdx.x < 64) {
        int gid = blockIdx.x * 256 + tid;          // 16384
        float run = 0.f;
#pragma unroll 8
        for (int c = 0; c < 128; ++c) {
            PRE[(size_t)c * 16384 + gid] = run;
            run += Cj[(size_t)c * 16384 + gid];
        }
        PRE[(size_t)128 * 16384 + gid] = run;
    } else {
        sCb[tid] = Cb[tid];
        sCb[tid + 256] = Cb[tid + 256];
        sCb[tid + 512] = Cb[tid + 512];
        sCb[tid + 768] = Cb[tid + 768];
        __syncthreads();
        if (tid < 8) {
            float run = 0.f;
            for (int c = 0; c < 128; ++c) {
                CbPre[c * 8 + tid] = run;
                run += sCb[c * 8 + tid];
            }
            CbPre[1024 + tid] = run;
        }
    }
}

// ====== k_combw: comb [0,1024) | wnodem [1024,2048) | bnode-MFMA [2048,2064) ======
__global__ __launch_bounds__(256) void k_combw(const ushort* __restrict__ qp,
                                               const float* __restrict__ s_g,
                                               const int* __restrict__ perm,
                                               const float* __restrict__ PRE,
                                               const float* __restrict__ CbPre,
                                               ushort* __restrict__ qdifb,
                                               const ushort* __restrict__ embbf,
                                               const ushort* __restrict__ WeTT,
                                               ushort* __restrict__ WnT,
                                               const float* __restrict__ be,
                                               float* __restrict__ bn) {
    __shared__ int ns[32];
    __shared__ float sa[32], sb[32];
    int id = blockIdx.x, tid = threadIdx.x;
    if (id < 1024) {
        int bx = id & 127, by = id >> 7;
        if (tid < 32) {
            int n = perm[bx * 32 + tid];
            ns[tid] = n;
            float s = s_g[n];
            sa[tid] = __expf(s);
            sb[tid] = __expf(-s);
        }
        __syncthreads();
        int j = by * 256 + tid;
        float T[8], pre[8];
        {
            const float* pp = PRE + (size_t)bx * 16384 + (size_t)j * 8;
            float4 u0 = *(const float4*)pp, u1 = *(const float4*)(pp + 4);
            pre[0] = u0.x; pre[1] = u0.y; pre[2] = u0.z; pre[3] = u0.w;
            pre[4] = u1.x; pre[5] = u1.y; pre[6] = u1.z; pre[7] = u1.w;
            const float* tp = PRE + (size_t)128 * 16384 + (size_t)j * 8;
            float4 t0 = *(const float4*)tp, t1 = *(const float4*)(tp + 4);
            T[0] = t0.x; T[1] = t0.y; T[2] = t0.z; T[3] = t0.w;
            T[4] = t1.x; T[5] = t1.y; T[6] = t1.z; T[7] = t1.w;
        }
        float TB[8], preb[8];
        {
            float4 v0 = *(const float4*)&CbPre[bx * 8], v1 = *(const float4*)&CbPre[bx * 8 + 4];
            preb[0] = v0.x; preb[1] = v0.y; preb[2] = v0.z; preb[3] = v0.w;
            preb[4] = v1.x; preb[5] = v1.y; preb[6] = v1.z; preb[7] = v1.w;
            float4 t0 = *(const float4*)&CbPre[1024], t1 = *(const float4*)&CbPre[1028];
            TB[0] = t0.x; TB[1] = t0.y; TB[2] = t0.z; TB[3] = t0.w;
            TB[4] = t1.x; TB[5] = t1.y; TB[6] = t1.z; TB[7] = t1.w;
        }
#pragma unroll 2
        for (int ii = 0; ii < 32; ++ii) {
            int n = ns[ii];
            float a = sa[ii], b = sb[ii];
            float g0 = 0.36787944117144233f;       // e^{-1}
            float g1 = g0 * a;
            float g2 = g1 * a * 0.5f;
            float g3 = g2 * a * (1.f / 3.f);
            float g4 = g3 * a * 0.25f;
            float g5 = g4 * a * 0.2f;
            float g6 = g5 * a * (1.f / 6.f);
            float g7 = g6 * a * (1.f / 7.f);
            float Z = a * preb[1]
                    + g0 * (TB[0] - preb[0]) + g1 * (TB[1] - preb[1])
                    + g2 * (TB[2] - preb[2]) + g3 * (TB[3] - preb[3])
                    + g4 * (TB[4] - preb[4]) + g5 * (TB[5] - preb[5])
                    + g6 * (TB[6] - preb[6]) + g7 * (TB[7] - preb[7]);
            float izv = 1.f / Z;
            float qv = b2f(qp[(size_t)n * 2048 + j]);
            float ss2 = g0 * (T[0] - pre[0]) + g1 * (T[1] - pre[1])
                      + g2 * (T[2] - pre[2]) + g3 * (T[3] - pre[3])
                      + g4 * (T[4] - pre[4]) + g5 * (T[5] - pre[5])
                      + g6 * (T[6] - pre[6]) + g7 * (T[7] - pre[7]);
            float outv = (a * pre[1] + ss2) * izv + qv;
            qdifb[(size_t)n * 2048 + j] = f2b(outv);
            float bk = 1.f;
#pragma unroll
            for (int k2 = 0; k2 < 8; ++k2) { pre[k2] += bk * qv; preb[k2] += bk; bk *= b; }
        }
    } else if (id < 2048) {
        int w2 = id - 1024;
        int lane = tid & 63, wid = tid >> 6;
        int n0  = (w2 & 31) * 128 + (wid >> 1) * 64;
        int od0 = (w2 >> 5) * 128 + (wid & 1) * 64;
        int l15 = lane & 15, kb = lane >> 4;
        short8 af[4], bf[4];
#pragma unroll
        for (int f = 0; f < 4; ++f) {
            af[f] = *(const short8*)(embbf + (size_t)(n0 + f * 16 + l15) * 32 + kb * 8);
            bf[f] = *(const short8*)(WeTT + (size_t)(od0 + f * 16 + l15) * 32 + kb * 8);
        }
        f32x4 acc[4][4] = {};
#pragma unroll
        for (int i = 0; i < 4; ++i)
#pragma unroll
            for (int j = 0; j < 4; ++j)
                acc[i][j] = MFMA16(af[i], bf[j], acc[i][j]);
#pragma unroll
        for (int i = 0; i < 4; ++i)
#pragma unroll
            for (int j = 0; j < 4; ++j)
#pragma unroll
                for (int r = 0; r < 4; ++r)
                    WnT[(size_t)(n0 + i * 16 + kb * 4 + r) * 4096 + od0 + j * 16 + l15] =
                        f2b(acc[i][j][r]);
    } else {                                         // ---- bnode = embbf @ be^T (MFMA, K=32)
        int blk = id - 2048;
        int lane = tid & 63, wid = tid >> 6;
        int n0 = blk * 256 + wid * 64;
        int l15 = lane & 15, kb = lane >> 4;
        short8 af[4], bf[4];
#pragma unroll
        for (int f = 0; f < 4; ++f)
            af[f] = *(const short8*)(embbf + (size_t)(n0 + f * 16 + l15) * 32 + kb * 8);
#pragma unroll
        for (int j = 0; j < 4; ++j) {
            short8 v;
#pragma unroll
            for (int i = 0; i < 8; ++i)
                v[i] = (short)f2b(be[(kb * 8 + i) * 64 + j * 16 + l15]);
            bf[j] = v;
        }
        f32x4 acc[4][4] = {};
#pragma unroll
        for (int i = 0; i < 4; ++i)
#pragma unroll
            for (int j = 0; j < 4; ++j)
                acc[i][j] = MFMA16(af[i], bf[j], acc[i][j]);
#pragma unroll
        for (int i = 0; i < 4; ++i)
#pragma unroll
            for (int j = 0; j < 4; ++j)
#pragma unroll
                for (int r = 0; r < 4; ++r)
                    bn[(size_t)(n0 + i * 16 + kb * 4 + r) * 64 + j * 16 + l15] = acc[i][j][r];
    }
}

// ---- fused (r16/r18 version): 4 waves/batch (w0:K, w1:V, w2:Q(0,1), w3:Q(2,3)) ----
__global__ __launch_bounds__(256, 2) void k_fused(const float* __restrict__ kin,
                                                  const float* __restrict__ vin,
                                                  const ushort* __restrict__ qdifb,
                                                  const ushort* __restrict__ WnT,
                                                  const float* __restrict__ bn,
                                                  const ushort* __restrict__ Wkbf,
                                                  const float* __restrict__ bk,
                                                  const ushort* __restrict__ Wvbf,
                                                  const float* __restrict__ bv,
                                                  const ushort* __restrict__ Wobf,
                                                  const float* __restrict__ bo,
                                                  float* __restrict__ out) {
    __shared__ ushort Kb[2176];       // [h][s][d1]  h stride 272
    __shared__ ushort Qb[2176];
    __shared__ ushort Vb[2560];       // [h][d1][s]  h stride 320, d1 stride 40
    __shared__ ushort Pb[4][1280];    // per-wave [t][s] t stride 40
    __shared__ ushort attb[2304];     // [t][d64] stride 72
    int tid = threadIdx.x, lane = tid & 63, w = tid >> 6;
    int b = blockIdx.x;
    int l15 = lane & 15, g = lane >> 4;
    int hh_w = l15 >> 3, d1_w = l15 & 7;
    const float SCALE = 0.35355339059327373f;   // 1/sqrt(8)
    short8 zfrag = {};

    f32x4 wx0, wx1, wx2, wx3, wx4, wx5, wx6, wx7;
    f32x4 x0, x1, x2, x3, x4, x5, x6, x7;
    float bxc0, bxc1, bxc2, bxc3;
    f32x4 q0v, q1v, q2v, q3v;
    f32x4 wn0, wn1, wn2, wn3;
    float bnc0, bnc1;
    f32x4 wo0, wo1; float boc;

    if (w < 2) {
        const float*  xin = w ? vin : kin;
        const ushort* Wx  = w ? Wvbf : Wkbf;
        const float*  bx_ = w ? bv : bk;
        unsigned long long bxA = (unsigned long long)(bx_ + l15);
        unsigned long long wxA = (unsigned long long)((const char*)Wx + l15 * 128 + g * 16 + 3072);
        unsigned long long xaA = (unsigned long long)(xin + (size_t)b * TD + (8 + l15) * 64 + g * 8);
        bxc0 = gl4<0>(bxA); bxc1 = gl4<64>(bxA); bxc2 = gl4<128>(bxA); bxc3 = gl4<192>(bxA);
        wx0 = gl16<-3072>(wxA); wx1 = gl16<-3008>(wxA);
        wx2 = gl16<-1024>(wxA); wx3 = gl16< -960>(wxA);
        wx4 = gl16< 1024>(wxA); wx5 = gl16< 1088>(wxA);
        wx6 = gl16< 3072>(wxA); wx7 = gl16< 3136>(wxA);
        x0 = gl16<-2048>(xaA); x1 = gl16<-2032>(xaA);
        x2 = gl16<-1920>(xaA); x3 = gl16<-1904>(xaA);
        x4 = gl16< 2048>(xaA); x5 = gl16< 2064>(xaA);
        x6 = gl16< 2176>(xaA); x7 = gl16< 2192>(xaA);
    } else {
        int wq = w - 2;
        unsigned long long qaA = (unsigned long long)(qdifb + (size_t)b * TD + (8 + l15) * 64 + g * 8);
        unsigned long long wnA = (unsigned long long)((const char*)(WnT + (size_t)b * 4096)
                                                      + ((size_t)(wq * 32 + l15)) * 128 + g * 16);
        unsigned long long bnA = (unsigned long long)(bn + (size_t)b * 64 + wq * 32 + l15);
        q0v = gl16<-1024>(qaA); q1v = gl16<-960>(qaA);
        q2v = gl16< 1024>(qaA); q3v = gl16<1088>(qaA);
        wn0 = gl16<0>(wnA); wn1 = gl16<64>(wnA);
        wn2 = gl16<2048>(wnA); wn3 = gl16<2112>(wnA);
        bnc0 = gl4<0>(bnA); bnc1 = gl4<64>(bnA);
    }
    {   // epilogue loads last -> stay in flight through attention
        unsigned long long woA = (unsigned long long)((const char*)Wobf
                                                      + ((size_t)(w * 16 + l15)) * 128 + g * 16);
        unsigned long long boA = (unsigned long long)(bo + w * 16 + l15);
        wo0 = gl16<0>(woA); wo1 = gl16<64>(woA);
        boc = gl4<0>(boA);
    }

    if (w < 2) {
        WAITV(3);
        short8 xaf[2][2], wxf[4][2];
        xaf[0][0] = pack8v(x0, x1); xaf[1][0] = pack8v(x2, x3);
        xaf[0][1] = pack8v(x4, x5); xaf[1][1] = pack8v(x6, x7);
        wxf[0][0] = as_s8(wx0); wxf[0][1] = as_s8(wx1);
        wxf[1][0] = as_s8(wx2); wxf[1][1] = as_s8(wx3);
        wxf[2][0] = as_s8(wx4); wxf[2][1] = as_s8(wx5);
        wxf[3][0] = as_s8(wx6); wxf[3][1] = as_s8(wx7);
        float bxc[4] = {bxc0, bxc1, bxc2, bxc3};
#pragma unroll
        for (int j = 0; j < 4; ++j) {
            f32x4 ax[2] = {};
#pragma unroll
            for (int kk = 0; kk < 2; ++kk)
#pragma unroll
                for (int ti = 0; ti < 2; ++ti)
                    ax[ti] = MFMA16(xaf[kk][ti], wxf[j][kk], ax[ti]);
            if (w == 0) {
#pragma unroll
                for (int ti = 0; ti < 2; ++ti)
#pragma unroll
                    for (int r = 0; r < 4; ++r) {
                        int s = ti * 16 + g * 4 + r;
                        Kb[(j * 2 + hh_w) * 272 + s * 8 + d1_w] = f2b(ax[ti][r] + bxc[j]);
                    }
            } else {
#pragma unroll
                for (int ti = 0; ti < 2; ++ti)
#pragma unroll
                    for (int r = 0; r < 4; r += 2) {
                        int s = ti * 16 + g * 4 + r;
                        ushort2 p; p.x = f2b(ax[ti][r] + bxc[j]); p.y = f2b(ax[ti][r + 1] + bxc[j]);
                        *(ushort2*)&Vb[(j * 2 + hh_w) * 320 + d1_w * 40 + s] = p;
                    }
            }
        }
    } else {
        int wq = w - 2;
        WAITV(3);
        short8 qaf[2][2], wnf[2][2];
        qaf[0][0] = as_s8(q0v); qaf[1][0] = as_s8(q1v);
        qaf[0][1] = as_s8(q2v); qaf[1][1] = as_s8(q3v);
        wnf[0][0] = as_s8(wn0); wnf[0][1] = as_s8(wn1);
        wnf[1][0] = as_s8(wn2); wnf[1][1] = as_s8(wn3);
        float bnc[2] = {bnc0, bnc1};
#pragma unroll
        for (int jj = 0; jj < 2; ++jj) {
            int j = 2 * wq + jj;
            f32x4 aq[2] = {};
#pragma unroll
            for (int kk = 0; kk < 2; ++kk)
#pragma unroll
                for (int ti = 0; ti < 2; ++ti)
                    aq[ti] = MFMA16(qaf[kk][ti], wnf[jj][kk], aq[ti]);
#pragma unroll
            for (int ti = 0; ti < 2; ++ti)
#pragma unroll
                for (int r = 0; r < 4; ++r) {
                    int s = ti * 16 + g * 4 + r;
                    Qb[(j * 2 + hh_w) * 272 + s * 8 + d1_w] = f2b(aq[ti][r] + bnc[jj]);
                }
        }
    }
    __syncthreads();

    // ======== attention: 2 heads per wave (h = 2w, 2w+1) ========
#pragma unroll
    for (int hh = 0; hh < 2; ++hh) {
        int h = 2 * w + hh;
        short8 kf[2], qf[2];
#pragma unroll
        for (int si = 0; si < 2; ++si)
            kf[si] = (lane < 16) ? *(const short8*)&Kb[h * 272 + (si * 16 + l15) * 8] : zfrag;
#pragma unroll
        for (int ti = 0; ti < 2; ++ti)
            qf[ti] = (lane < 16) ? *(const short8*)&Qb[h * 272 + (ti * 16 + l15) * 8] : zfrag;
        f32x4 sc[2][2];
#pragma unroll
        for (int si = 0; si < 2; ++si)
#pragma unroll
            for (int ti = 0; ti < 2; ++ti)
                sc[si][ti] = MFMA16(kf[si], qf[ti], f32x4{});
#pragma unroll
        for (int ti = 0; ti < 2; ++ti) {
            float e0[4], e1[4], sm = 0.f;
#pragma unroll
            for (int r = 0; r < 4; ++r) {
                e0[r] = __expf(sc[0][ti][r] * SCALE);
                e1[r] = __expf(sc[1][ti][r] * SCALE);
                sm += e0[r] + e1[r];
            }
            sm += __shfl_xor(sm, 16);
            sm += __shfl_xor(sm, 32);
            float inv = 1.f / sm;
            int t = ti * 16 + l15;
            unsigned p00 = (unsigned)f2b(e0[0] * inv) | ((unsigned)f2b(e0[1] * inv) << 16);
            unsigned p01 = (unsigned)f2b(e0[2] * inv) | ((unsigned)f2b(e0[3] * inv) << 16);
            unsigned p10 = (unsigned)f2b(e1[0] * inv) | ((unsigned)f2b(e1[1] * inv) << 16);
            unsigned p11 = (unsigned)f2b(e1[2] * inv) | ((unsigned)f2b(e1[3] * inv) << 16);
            *(unsigned*)&Pb[w][t * 40 + g * 4]          = p00;
            *(unsigned*)&Pb[w][t * 40 + g * 4 + 2]      = p01;
            *(unsigned*)&Pb[w][t * 40 + 16 + g * 4]     = p10;
            *(unsigned*)&Pb[w][t * 40 + 16 + g * 4 + 2] = p11;
        }
        short8 vf = *(const short8*)&Vb[h * 320 + (l15 & 7) * 40 + g * 8];
#pragma unroll
        for (int ti = 0; ti < 2; ++ti) {
            short8 af = *(const short8*)&Pb[w][(ti * 16 + l15) * 40 + g * 8];
            f32x4 pv = MFMA16(af, vf, f32x4{});
            if (l15 < 8) {
#pragma unroll
                for (int r = 0; r < 4; ++r)
                    attb[(ti * 16 + g * 4 + r) * 72 + h * 8 + l15] = f2b(pv[r]);
            }
        }
    }
    __syncthreads();

    // ======== epilogue: this wave's column tile j = w ========
    WAITV(0);
    {
        short8 wof[2];
        wof[0] = as_s8(wo0); wof[1] = as_s8(wo1);
        short8 aof[2][2];
#pragma unroll
        for (int kk = 0; kk < 2; ++kk)
#pragma unroll
            for (int ti = 0; ti < 2; ++ti)
                aof[kk][ti] = *(const short8*)&attb[(ti * 16 + l15) * 72 + kk * 32 + g * 8];
        f32x4 co[2] = {};
#pragma unroll
        for (int kk = 0; kk < 2; ++kk)
#pragma unroll
            for (int ti = 0; ti < 2; ++ti)
                co[ti] = MFMA16(aof[kk][ti], wof[kk], co[ti]);
#pragma unroll
        for (int ti = 0; ti < 2; ++ti)
#pragma unroll
            for (int r = 0; r < 4; ++r)
                out[(size_t)b * TD + (ti * 16 + g * 4 + r) * 64 + w * 16 + l15] =
                    co[ti][r] + boc;
    }
}

extern "C" void kernel_launch(void* const* d_in, const int* in_sizes, int n_in,
                              void* d_out, int out_size, void* d_ws, size_t ws_size,
                              hipStream_t stream) {
    const float* q   = (const float*)d_in[0];
    const float* k   = (const float*)d_in[1];
    const float* v   = (const float*)d_in[2];
    const float* emb = (const float*)d_in[3];
    const float* We  = (const float*)d_in[4];
    const float* be  = (const float*)d_in[5];
    const float* Wq  = (const float*)d_in[6];
    const float* bq  = (const float*)d_in[7];
    const float* Wk  = (const float*)d_in[8];
    const float* bk  = (const float*)d_in[9];
    const float* Wv  = (const float*)d_in[10];
    const float* bv  = (const float*)d_in[11];
    const float* Wo  = (const float*)d_in[12];
    const float* bo  = (const float*)d_in[13];

    float* ws = (float*)d_ws;
    ushort* qp    = (ushort*)ws;                          // 16 MB (bf16)
    ushort* WnT   = (ushort*)(ws + 4194304);              // 32 MB
    ushort* qdifb = (ushort*)(ws + 12582912);             // 16 MB
    float*  Cj    = ws + 16777216;                        // 8 MB (128 chunks)
    float*  bn    = ws + 18874368;                        // 1 MB
    float*  s_g   = ws + 19136512;                        // 16 KB
    int*    perm  = (int*)(ws + 19140608);                // 16 KB
    float*  Cb    = ws + 19144704;                        // 4 KB
    ushort* embbf = (ushort*)(ws + 19145728);             // 256 KB
    ushort* WeTT  = (ushort*)(ws + 19211264);             // 256 KB
    ushort* Wkbf  = (ushort*)(ws + 19276800);             // 8 KB
    ushort* Wvbf  = (ushort*)(ws + 19278848);             // 8 KB
    ushort* Wobf  = (ushort*)(ws + 19280896);             // 8 KB
    float*  PRE   = ws + 19282944;                        // 8.45 MB (129 x 16384)
    float*  CbPre = ws + 21396480;                        // 4.1 KB (end ~85.6 MB)
    float*  outp  = (float*)d_out;

    k_prep <<<224, 256, 0, stream>>>(emb, We, Wk, Wv, Wo,
                                     s_g, embbf, WeTT, Wkbf, Wvbf, Wobf);
    k_pr   <<<1024, 256, 0, stream>>>(q, Wq, bq, qp, s_g, perm);
    k_csum <<<dim3(128, 8), 256, 0, stream>>>(qp, s_g, perm, Cj, Cb);
    k_pre  <<<65, 256, 0, stream>>>(Cj, PRE, Cb, CbPre);
    k_combw<<<2064, 256, 0, stream>>>(qp, s_g, perm, PRE, CbPre, qdifb,
                                      embbf, WeTT, WnT, be, bn);
    k_fused<<<4096, 256, 0, stream>>>(k, v, qdifb, WnT, bn,
                                      Wkbf, bk, Wvbf, bv, Wobf, bo, outp);
}